// Round 1
// 414.470 us; speedup vs baseline: 1.0254x; 1.0254x over previous
//
#include <hip/hip_runtime.h>
#include <math.h>

// Problem constants (fixed shapes from setup_inputs)
constexpr int TOPK = 8;
constexpr int NUM_SPECIAL = 999;
constexpr int V = 30522;
constexpr int D = 768;
constexpr int BLOCK = 256;
// Row base is only 8B-aligned when pos is odd (V%4==2). We peel 2 floats
// (tail for even pos, head for odd pos) so the float4 body is 16B-aligned.
constexpr int V4 = 7630;                       // aligned float4 count per row
constexpr int NK4 = (V4 + BLOCK - 1) / BLOCK;  // 30 float4 per thread stream
constexpr int CAP = 512;                       // candidate buffer (ties safety)
constexpr int HOTCAP = 64;                     // hot-thread list bound

// Monotone map float -> uint32 (order-preserving), packed with ~idx so that
// larger key == (larger value, then SMALLER index) -- matches jax.lax.top_k
// tie-breaking (lower index first among equal values).
__device__ __forceinline__ unsigned long long fkey(float v, unsigned int idx) {
    unsigned int u = __float_as_uint(v);
    u = ((int)u < 0) ? ~u : (u | 0x80000000u);
    return ((unsigned long long)u << 32) | (unsigned long long)(~idx);
}

// branchless sorted-desc top-8 insert (2 VALU per stage: v_max/v_min)
__device__ __forceinline__ void net8(float (&L)[TOPK], float t) {
    #pragma unroll
    for (int j = 0; j < TOPK; ++j) {
        float m = fmaxf(L[j], t); t = fminf(L[j], t); L[j] = m;
    }
}

// Per-wave exact top-8 extraction from 64 sorted-desc 8-lists (pops heads).
// Deterministic tie-break by lane id. lane 0 writes the 8 values to dst[0..8).
__device__ __forceinline__ void wave_extract8(float (&cur)[TOPK], int lane,
                                              float* dst) {
    #pragma unroll
    for (int r = 0; r < TOPK; ++r) {
        float m = cur[0];
        int ml = lane;
        #pragma unroll
        for (int off = 1; off < 64; off <<= 1) {
            float om = __shfl_xor(m, off, 64);
            int   ol = __shfl_xor(ml, off, 64);
            if (om > m || (om == m && ol < ml)) { m = om; ml = ol; }
        }
        if (lane == ml) {                      // winner pops its head
            #pragma unroll
            for (int j = 0; j < TOPK - 1; ++j) cur[j] = cur[j + 1];
            cur[TOPK - 1] = -INFINITY;
        }
        if (lane == 0) dst[r] = m;
    }
}

__global__ __launch_bounds__(BLOCK, 8) void dvat_kernel(
    const float* __restrict__ delta_grad,   // [B,S,D]
    const float* __restrict__ src_embeds,   // [B,S,D]
    const float* __restrict__ emb,          // [V,D]
    const int*   __restrict__ src_tokens,   // [B,S]
    const float* __restrict__ pred_lm,      // [B,S,V]
    const int*   __restrict__ attn,         // [B,S]
    const float* __restrict__ rand_u,       // [B,S]
    int* __restrict__ out)                  // [B,S]
{
    const int pos = blockIdx.x;        // b*S + s
    const int tid = threadIdx.x;
    const int lane = tid & 63;
    const int wave = tid >> 6;

    __shared__ float  smax[BLOCK];                // per-thread stream maxes
    __shared__ float  sm8[TOPK];
    __shared__ float  s_g8;
    __shared__ int    s_hot[HOTCAP];
    __shared__ int    s_nhot;
    __shared__ int    s_ncand;
    __shared__ unsigned long long sh_cand64[CAP]; // 4 KB
    __shared__ int    s_cand[TOPK];
    __shared__ double s_scores[TOPK];
    __shared__ double s_pd[4], s_ssq[4];
    __shared__ float4 shf4[2 * D / 4];            // dg row | se row (6 KB, 16B-aligned)

    if (tid == 0) { s_nhot = 0; s_ncand = 0; }

    const float* rowf = pred_lm + (size_t)pos * V;
    const int ofs = (pos & 1) << 1;               // 0 (even pos) or 2 (odd pos)
    const float4* row4 = (const float4*)(rowf + ofs);   // 16B-aligned body

    // ---------------- Pass 1: per-thread stream MAX (memory-bound) ----------
    // tau = 8th-largest of the 256 stream maxes is a valid threshold <= true
    // g8: the true top-8 live in <=8 threads, so the 8th-largest thread-max
    // is <= v8. 1 fmax/element instead of the old 16-op top-8 network.
    float m0 = -INFINITY, m1 = -INFINITY, m2 = -INFINITY, m3 = -INFINITY;
    int i = tid;
    for (int q = 0; q < 7; ++q, i += 4 * BLOCK) { // 28*256 = 7168 float4
        float4 a = row4[i];
        float4 b = row4[i + BLOCK];
        float4 c = row4[i + 2 * BLOCK];
        float4 d = row4[i + 3 * BLOCK];
        m0 = fmaxf(m0, fmaxf(fmaxf(a.x, a.y), fmaxf(a.z, a.w)));
        m1 = fmaxf(m1, fmaxf(fmaxf(b.x, b.y), fmaxf(b.z, b.w)));
        m2 = fmaxf(m2, fmaxf(fmaxf(c.x, c.y), fmaxf(c.z, c.w)));
        m3 = fmaxf(m3, fmaxf(fmaxf(d.x, d.y), fmaxf(d.z, d.w)));
    }
    for (; i < V4; i += BLOCK) {                  // tail: 462 float4
        float4 a = row4[i];
        m0 = fmaxf(m0, fmaxf(fmaxf(a.x, a.y), fmaxf(a.z, a.w)));
    }
    const float tm = fmaxf(fmaxf(m0, m1), fmaxf(m2, m3));
    smax[tid] = tm;
    __syncthreads();

    // ---------------- Pass 2: tau = 8th-largest of 256 maxes ----------------
    if (wave == 0) {
        float L[TOPK];
        #pragma unroll
        for (int j = 0; j < TOPK; ++j) L[j] = -INFINITY;
        net8(L, smax[lane]);
        net8(L, smax[lane + 64]);
        net8(L, smax[lane + 128]);
        net8(L, smax[lane + 192]);
        wave_extract8(L, lane, sm8);
        if (lane == 0) s_g8 = sm8[TOPK - 1];      // 8th extracted
    }
    __syncthreads();
    const float g8 = s_g8;                        // tau <= true g8

    // ---------------- hot threads: stream may contain a candidate ----------
    // Exactly ~8 threads (those whose max is among the top-8 maxes, + ties).
    if (tm >= g8) {
        int p = atomicAdd(&s_nhot, 1);
        if (p < HOTCAP) s_hot[p] = tid;
    }
    __syncthreads();

    // The 2 floats outside the aligned float4 body, checked directly.
    // (They were excluded from the maxes; tau over a sub-partition is still
    //  <= global g8, and they get pushed here if they are candidates.)
    if (tid == 0) {
        #pragma unroll
        for (int e = 0; e < 2; ++e) {
            const int idx = ofs ? e : (V4 * 4 + e);
            const float f = rowf[idx];
            if (f >= g8) {
                int p = atomicAdd(&s_ncand, 1);
                if (p < CAP) sh_cand64[p] = fkey(f, (unsigned)idx);
            }
        }
    }

    // ---------------- sparse rescan of hot streams (L2/L3-resident) --------
    if (s_nhot <= HOTCAP) {
        const int nhot = s_nhot;
        const int total = nhot * NK4;
        for (int w = tid; w < total; w += BLOCK) {
            const int h = w / NK4;                // const-div -> magic mul
            const int k = w - h * NK4;
            const int i4 = s_hot[h] + (k << 8);   // stride BLOCK in float4 space
            if (i4 < V4) {
                const float4 f = row4[i4];
                const int base = ofs + 4 * i4;
                if (f.x >= g8) { int p = atomicAdd(&s_ncand, 1); if (p < CAP) sh_cand64[p] = fkey(f.x, (unsigned)base); }
                if (f.y >= g8) { int p = atomicAdd(&s_ncand, 1); if (p < CAP) sh_cand64[p] = fkey(f.y, (unsigned)(base + 1)); }
                if (f.z >= g8) { int p = atomicAdd(&s_ncand, 1); if (p < CAP) sh_cand64[p] = fkey(f.z, (unsigned)(base + 2)); }
                if (f.w >= g8) { int p = atomicAdd(&s_ncand, 1); if (p < CAP) sh_cand64[p] = fkey(f.w, (unsigned)(base + 3)); }
            }
        }
    } else {                                      // massive-tie fallback: full rescan
        for (int i4 = tid; i4 < V4; i4 += BLOCK) {
            const float4 f = row4[i4];
            const int base = ofs + 4 * i4;
            if (f.x >= g8) { int p = atomicAdd(&s_ncand, 1); if (p < CAP) sh_cand64[p] = fkey(f.x, (unsigned)base); }
            if (f.y >= g8) { int p = atomicAdd(&s_ncand, 1); if (p < CAP) sh_cand64[p] = fkey(f.y, (unsigned)(base + 1)); }
            if (f.z >= g8) { int p = atomicAdd(&s_ncand, 1); if (p < CAP) sh_cand64[p] = fkey(f.z, (unsigned)(base + 2)); }
            if (f.w >= g8) { int p = atomicAdd(&s_ncand, 1); if (p < CAP) sh_cand64[p] = fkey(f.w, (unsigned)(base + 3)); }
        }
    }
    __syncthreads();
    const int ncand = min(s_ncand, CAP);          // >= 8 by construction

    // ---------------- exact top-8 (value desc, index asc) -------------------
    for (int it = 0; it < TOPK; ++it) {
        if (tid < 64) {
            unsigned long long m = 0ull; int ms = 0;
            for (int j = tid; j < ncand; j += 64) {
                unsigned long long x = sh_cand64[j];
                if (x > m) { m = x; ms = j; }
            }
            #pragma unroll
            for (int off = 32; off; off >>= 1) {
                unsigned long long om = __shfl_down(m, off, 64);
                int os = __shfl_down(ms, off, 64);
                if (om > m) { m = om; ms = os; }
            }
            if (tid == 0) {
                s_cand[it] = (m == 0ull) ? 0 : (int)(~(unsigned int)m);
                sh_cand64[ms] = 0ull;
            }
        }
        __syncthreads();
    }

    // topk_idx *= attention_mask  (mask==0 -> all candidates index 0)
    if (tid == 0 && attn[pos] == 0) {
        #pragma unroll
        for (int k = 0; k < TOPK; ++k) s_cand[k] = 0;
    }
    __syncthreads();

    // ---------------- stage dg/se rows in LDS + prev_dot/src_sq -------------
    const float* dg = delta_grad + (size_t)pos * D;
    const float* se = src_embeds + (size_t)pos * D;

    double pd = 0.0, ssq = 0.0;
    for (int ii = tid; ii < D / 4; ii += BLOCK) { // 192 float4
        const float4 g = ((const float4*)dg)[ii];
        const float4 e = ((const float4*)se)[ii];
        shf4[ii] = g;
        shf4[D / 4 + ii] = e;
        pd  += (double)g.x * (double)e.x + (double)g.y * (double)e.y
             + (double)g.z * (double)e.z + (double)g.w * (double)e.w;
        ssq += (double)e.x * (double)e.x + (double)e.y * (double)e.y
             + (double)e.z * (double)e.z + (double)e.w * (double)e.w;
    }
    #pragma unroll
    for (int off = 32; off; off >>= 1) {
        pd  += __shfl_down(pd, off, 64);
        ssq += __shfl_down(ssq, off, 64);
    }
    if (lane == 0) { s_pd[wave] = pd; s_ssq[wave] = ssq; }
    __syncthreads();

    const double prev_dot = s_pd[0] + s_pd[1] + s_pd[2] + s_pd[3];
    const double src_sq   = s_ssq[0] + s_ssq[1] + s_ssq[2] + s_ssq[3];

    // ---------------- score 8 candidates (2 per wave, fp64) -----------------
    #pragma unroll
    for (int kk = 0; kk < 2; ++kk) {
        const int k = 2 * wave + kk;
        const int v = s_cand[k];
        const float4* ev4 = (const float4*)(emb + (size_t)v * D);
        double ddg = 0.0, dse = 0.0, dvv = 0.0;
        for (int ii = lane; ii < D / 4; ii += 64) {   // 3 iterations
            const float4 e = ev4[ii];
            const float4 g = shf4[ii];
            const float4 s = shf4[D / 4 + ii];
            ddg += (double)e.x * (double)g.x + (double)e.y * (double)g.y
                 + (double)e.z * (double)g.z + (double)e.w * (double)g.w;
            dse += (double)e.x * (double)s.x + (double)e.y * (double)s.y
                 + (double)e.z * (double)s.z + (double)e.w * (double)s.w;
            dvv += (double)e.x * (double)e.x + (double)e.y * (double)e.y
                 + (double)e.z * (double)e.z + (double)e.w * (double)e.w;
        }
        #pragma unroll
        for (int off = 32; off; off >>= 1) {
            ddg += __shfl_down(ddg, off, 64);
            dse += __shfl_down(dse, off, 64);
            dvv += __shfl_down(dvv, off, 64);
        }
        if (lane == 0) {
            double sq = src_sq + dvv - 2.0 * dse;
            if (sq < 0.0) sq = 0.0;
            double dn = sqrt(sq + 1e-20);
            s_scores[k] = (ddg - prev_dot) / dn;   // dir_dot_grad / dir_norm
        }
    }
    __syncthreads();

    // ---------------- filtered argmax + swap blend (thread 0) ---------------
    if (tid == 0) {
        const int src_tok = src_tokens[pos];
        int best = 0;
        double best_s = 0.0;
        bool found = false;
        #pragma unroll
        for (int k = 0; k < TOPK; ++k) {
            const int v = s_cand[k];
            if (v < NUM_SPECIAL || v == src_tok) continue;   // -inf in reference
            const double sc = s_scores[k];
            // jnp.argmax: lowest index wins ties
            if (!found || sc > best_s || (sc == best_s && v < best)) {
                best = v; best_s = sc; found = true;
            }
        }
        const int adv_flip = found ? best : 0;   // argmax of all -inf -> 0
        const bool no_special = (src_tok >= NUM_SPECIAL);
        const bool swap = (rand_u[pos] > 0.7f);  // 1.0 - SWAP_RATIO in f32
        out[pos] = (no_special && swap) ? adv_flip : src_tok;
    }
}

extern "C" void kernel_launch(void* const* d_in, const int* in_sizes, int n_in,
                              void* d_out, int out_size, void* d_ws, size_t ws_size,
                              hipStream_t stream) {
    const float* delta_grad = (const float*)d_in[0];
    const float* src_embeds = (const float*)d_in[1];
    const float* emb        = (const float*)d_in[2];
    const int*   src_tokens = (const int*)d_in[3];
    const float* pred_lm    = (const float*)d_in[4];
    const int*   attn       = (const int*)d_in[5];
    const float* randu      = (const float*)d_in[6];
    int* out = (int*)d_out;

    const int BS = in_sizes[3];   // B*S = 2048 positions
    dvat_kernel<<<BS, BLOCK, 0, stream>>>(delta_grad, src_embeds, emb,
                                          src_tokens, pred_lm, attn, randu, out);
}